// Round 1
// baseline (397.992 us; speedup 1.0000x reference)
//
#include <hip/hip_runtime.h>
#include <hip/hip_bf16.h>

#define DIM 512
#define NHEAD 8
#define HD 64
#define SEQ 2048
#define BATCH 4
#define NROWS (BATCH * SEQ)  // 8192

typedef __bf16 bf16;
typedef __bf16 bf16x8 __attribute__((ext_vector_type(8)));
typedef __bf16 bf16x4 __attribute__((ext_vector_type(4)));
typedef float f32x4 __attribute__((ext_vector_type(4)));
typedef unsigned short us8 __attribute__((ext_vector_type(8)));
typedef unsigned int u32x4 __attribute__((ext_vector_type(4)));

__device__ __forceinline__ f32x4 mfma16(bf16x8 a, bf16x8 b, f32x4 c) {
  return __builtin_amdgcn_mfma_f32_16x16x32_bf16(a, b, c, 0, 0, 0);
}

// ---------- transpose + f32->bf16 convert: in (R,C) -> out (C,R) ----------
template <int R, int C>
__global__ __launch_bounds__(256, 8) void convert_t(const float* __restrict__ in,
                                                    bf16* __restrict__ out) {
  int id = blockIdx.x * 256 + threadIdx.x;
  if (id >= R * C) return;
  int c = id / R;
  int r = id - c * R;
  out[id] = (bf16)in[r * C + c];
}

// ---------- layernorm over 512 cols, one wave per row, bf16 out ----------
__global__ __launch_bounds__(256, 8) void ln_kernel(const float* __restrict__ in,
                                                    const float* __restrict__ g,
                                                    const float* __restrict__ b,
                                                    bf16* __restrict__ out) {
  int row = blockIdx.x * 4 + (threadIdx.x >> 6);
  int lane = threadIdx.x & 63;
  const float4* p = (const float4*)(in + (size_t)row * DIM);
  float4 v0 = p[lane];
  float4 v1 = p[lane + 64];
  float s = v0.x + v0.y + v0.z + v0.w + v1.x + v1.y + v1.z + v1.w;
#pragma unroll
  for (int m = 1; m < 64; m <<= 1) s += __shfl_xor(s, m);
  float mean = s * (1.0f / DIM);
  float d0 = v0.x - mean, d1 = v0.y - mean, d2 = v0.z - mean, d3 = v0.w - mean;
  float d4 = v1.x - mean, d5 = v1.y - mean, d6 = v1.z - mean, d7 = v1.w - mean;
  float q = d0 * d0 + d1 * d1 + d2 * d2 + d3 * d3 + d4 * d4 + d5 * d5 + d6 * d6 + d7 * d7;
#pragma unroll
  for (int m = 1; m < 64; m <<= 1) q += __shfl_xor(q, m);
  float rstd = rsqrtf(q * (1.0f / DIM) + 1e-5f);
  const float4* gp = (const float4*)g;
  const float4* bp = (const float4*)b;
  float4 g0 = gp[lane], g1 = gp[lane + 64];
  float4 b0 = bp[lane], b1 = bp[lane + 64];
  bf16x4 oa, ob;
  oa[0] = (bf16)(d0 * rstd * g0.x + b0.x);
  oa[1] = (bf16)(d1 * rstd * g0.y + b0.y);
  oa[2] = (bf16)(d2 * rstd * g0.z + b0.z);
  oa[3] = (bf16)(d3 * rstd * g0.w + b0.w);
  ob[0] = (bf16)(d4 * rstd * g1.x + b1.x);
  ob[1] = (bf16)(d5 * rstd * g1.y + b1.y);
  ob[2] = (bf16)(d6 * rstd * g1.z + b1.z);
  ob[3] = (bf16)(d7 * rstd * g1.w + b1.w);
  *(bf16x4*)(out + (size_t)row * DIM + lane * 4) = oa;
  *(bf16x4*)(out + (size_t)row * DIM + 256 + lane * 4) = ob;
}

// ---------- GEMM: C = A(MxK,bf16,rm) * Bt(NxK,bf16,rm)^T + bias, epilogues ----------
#define GBM 128
#define GBN 128
#define GBK 64
#define LSTR 88  // LDS row stride in bf16 elems: 176B = 11*16B aligned, 2-way-free banks

enum { EPI_BF16 = 0, EPI_GELU = 1, EPI_RESID = 2 };

template <int EPI>
__global__ __launch_bounds__(256, 2) void gemm_bt(const bf16* __restrict__ A,
                                                  const bf16* __restrict__ Bt,
                                                  const float* __restrict__ bias,
                                                  const float* resid, void* outv,
                                                  int M, int N, int K) {
  __shared__ bf16 Al[GBM * LSTR];
  __shared__ bf16 Bl[GBN * LSTR];
  const int t = threadIdx.x;
  const int lane = t & 63;
  const int wave = t >> 6;
  const int wm = wave >> 1, wn = wave & 1;
  const int m0 = blockIdx.y * GBM, n0 = blockIdx.x * GBN;

  f32x4 acc[4][4] = {};

  const int srow = t >> 1;
  const int scol = (t & 1) * 32;
  const bf16* ga = A + (size_t)(m0 + srow) * K + scol;
  const bf16* gb = Bt + (size_t)(n0 + srow) * K + scol;
  bf16* la = &Al[srow * LSTR + scol];
  bf16* lb = &Bl[srow * LSTR + scol];

  for (int k0 = 0; k0 < K; k0 += GBK) {
    u32x4 ra0 = *(const u32x4*)(ga);
    u32x4 ra1 = *(const u32x4*)(ga + 8);
    u32x4 ra2 = *(const u32x4*)(ga + 16);
    u32x4 ra3 = *(const u32x4*)(ga + 24);
    u32x4 rb0 = *(const u32x4*)(gb);
    u32x4 rb1 = *(const u32x4*)(gb + 8);
    u32x4 rb2 = *(const u32x4*)(gb + 16);
    u32x4 rb3 = *(const u32x4*)(gb + 24);
    ga += GBK;
    gb += GBK;
    __syncthreads();
    ((u32x4*)la)[0] = ra0;
    ((u32x4*)la)[1] = ra1;
    ((u32x4*)la)[2] = ra2;
    ((u32x4*)la)[3] = ra3;
    ((u32x4*)lb)[0] = rb0;
    ((u32x4*)lb)[1] = rb1;
    ((u32x4*)lb)[2] = rb2;
    ((u32x4*)lb)[3] = rb3;
    __syncthreads();
#pragma unroll
    for (int kk = 0; kk < GBK; kk += 32) {
      bf16x8 af[4], bfr[4];
#pragma unroll
      for (int i = 0; i < 4; i++)
        af[i] = *(const bf16x8*)&Al[(wm * 64 + i * 16 + (lane & 15)) * LSTR + kk + (lane >> 4) * 8];
#pragma unroll
      for (int j = 0; j < 4; j++)
        bfr[j] = *(const bf16x8*)&Bl[(wn * 64 + j * 16 + (lane & 15)) * LSTR + kk + (lane >> 4) * 8];
#pragma unroll
      for (int i = 0; i < 4; i++)
#pragma unroll
        for (int j = 0; j < 4; j++) acc[i][j] = mfma16(af[i], bfr[j], acc[i][j]);
    }
  }
  const int rbase = (lane >> 4) * 4;
  const int cl = lane & 15;
#pragma unroll
  for (int i = 0; i < 4; i++) {
#pragma unroll
    for (int j = 0; j < 4; j++) {
      int col = n0 + wn * 64 + j * 16 + cl;
      float bv = bias[col];
#pragma unroll
      for (int r = 0; r < 4; r++) {
        int row = m0 + wm * 64 + i * 16 + rbase + r;
        float v = acc[i][j][r] + bv;
        size_t idx = (size_t)row * N + col;
        if constexpr (EPI == EPI_BF16) {
          ((bf16*)outv)[idx] = (bf16)v;
        } else if constexpr (EPI == EPI_GELU) {
          ((bf16*)outv)[idx] = (bf16)(0.5f * v * (1.0f + erff(v * 0.70710678118f)));
        } else {
          ((float*)outv)[idx] = resid[idx] + v;
        }
      }
    }
  }
}

// ---------- fused attention: per (b, h, 128 q-rows), flash-style ----------
#define KSTR 88
#define VSTR 136
#define PSTR 136

__global__ __launch_bounds__(256, 2) void attn_kernel(const bf16* __restrict__ qkv,
                                                      const float* __restrict__ Ab,
                                                      const float* __restrict__ edge_w,
                                                      const float* __restrict__ edge_scale,
                                                      bf16* __restrict__ out) {
  __shared__ bf16 Kl[128 * KSTR];
  __shared__ bf16 Vt[64 * VSTR];
  __shared__ bf16 Pl[4][32 * PSTR];
  const int i0 = blockIdx.x * 128;
  const int h = blockIdx.y;
  const int b = blockIdx.z;
  const int t = threadIdx.x, lane = t & 63, wave = t >> 6;
  const float es = edge_scale[0] * edge_w[h];

  const int rs = 3 * DIM;  // 1536
  const bf16* qbase = qkv + (size_t)b * SEQ * rs + h * HD;
  const bf16* kbase = qbase + DIM;
  const bf16* vbase = qbase + 2 * DIM;

  bf16x8 qf[2][2];
#pragma unroll
  for (int mf = 0; mf < 2; mf++)
#pragma unroll
    for (int kf = 0; kf < 2; kf++)
      qf[mf][kf] = *(const bf16x8*)(qbase + (size_t)(i0 + wave * 32 + mf * 16 + (lane & 15)) * rs +
                                    kf * 32 + (lane >> 4) * 8);

  float mrow[2][4], lrow[2][4];
  f32x4 oacc[2][4] = {};
#pragma unroll
  for (int mf = 0; mf < 2; mf++)
#pragma unroll
    for (int r = 0; r < 4; r++) {
      mrow[mf][r] = -1e30f;
      lrow[mf][r] = 0.0f;
    }

  const int srow = t >> 1, scol = (t & 1) * 32;
  const int jp = t & 63;
  const int doct0 = t >> 6;

  for (int jt = 0; jt < SEQ; jt += 128) {
    const bf16* krow = kbase + (size_t)(jt + srow) * rs + scol;
    u32x4 rk0 = *(const u32x4*)(krow);
    u32x4 rk1 = *(const u32x4*)(krow + 8);
    u32x4 rk2 = *(const u32x4*)(krow + 16);
    u32x4 rk3 = *(const u32x4*)(krow + 24);
    const bf16* vr0 = vbase + (size_t)(jt + 2 * jp) * rs;
    const bf16* vr1 = vr0 + rs;
    us8 va0 = *(const us8*)(vr0 + doct0 * 8);
    us8 va1 = *(const us8*)(vr1 + doct0 * 8);
    us8 vb0 = *(const us8*)(vr0 + (doct0 + 4) * 8);
    us8 vb1 = *(const us8*)(vr1 + (doct0 + 4) * 8);
    __syncthreads();
    {
      u32x4* lk = (u32x4*)&Kl[srow * KSTR + scol];
      lk[0] = rk0;
      lk[1] = rk1;
      lk[2] = rk2;
      lk[3] = rk3;
#pragma unroll
      for (int jj = 0; jj < 8; jj++) {
        unsigned w0 = (unsigned)va0[jj] | ((unsigned)va1[jj] << 16);
        *(unsigned*)&Vt[(doct0 * 8 + jj) * VSTR + 2 * jp] = w0;
        unsigned w1 = (unsigned)vb0[jj] | ((unsigned)vb1[jj] << 16);
        *(unsigned*)&Vt[((doct0 + 4) * 8 + jj) * VSTR + 2 * jp] = w1;
      }
    }
    __syncthreads();

    // S = Q K^T
    f32x4 s[2][8] = {};
#pragma unroll
    for (int kf = 0; kf < 2; kf++) {
      bf16x8 kfr[8];
#pragma unroll
      for (int nf = 0; nf < 8; nf++)
        kfr[nf] = *(const bf16x8*)&Kl[(nf * 16 + (lane & 15)) * KSTR + kf * 32 + (lane >> 4) * 8];
#pragma unroll
      for (int mf = 0; mf < 2; mf++)
#pragma unroll
        for (int nf = 0; nf < 8; nf++) s[mf][nf] = mfma16(qf[mf][kf], kfr[nf], s[mf][nf]);
    }

    // online softmax (scale + edge bias from A)
#pragma unroll
    for (int mf = 0; mf < 2; mf++) {
#pragma unroll
      for (int r = 0; r < 4; r++) {
        int irow = i0 + wave * 32 + mf * 16 + (lane >> 4) * 4 + r;
        const float* arow = Ab + ((size_t)b * SEQ + irow) * SEQ + jt + (lane & 15);
        float sv[8];
        float rmax = -1e30f;
#pragma unroll
        for (int nf = 0; nf < 8; nf++) {
          float val = s[mf][nf][r] * 0.125f + es * arow[nf * 16];
          sv[nf] = val;
          rmax = fmaxf(rmax, val);
        }
#pragma unroll
        for (int m = 1; m < 16; m <<= 1) rmax = fmaxf(rmax, __shfl_xor(rmax, m));
        float mprev = mrow[mf][r];
        float mnew = fmaxf(mprev, rmax);
        float corr = __expf(mprev - mnew);
        float psum = 0.0f;
        int prow = (mf * 16 + (lane >> 4) * 4 + r) * PSTR;
#pragma unroll
        for (int nf = 0; nf < 8; nf++) {
          float p = __expf(sv[nf] - mnew);
          psum += p;
          Pl[wave][prow + nf * 16 + (lane & 15)] = (bf16)p;
        }
#pragma unroll
        for (int m = 1; m < 16; m <<= 1) psum += __shfl_xor(psum, m);
        lrow[mf][r] = lrow[mf][r] * corr + psum;
        mrow[mf][r] = mnew;
#pragma unroll
        for (int nd = 0; nd < 4; nd++) oacc[mf][nd][r] *= corr;
      }
    }

    // O += P V
#pragma unroll
    for (int kf = 0; kf < 4; kf++) {
      bf16x8 pa[2], vv[4];
#pragma unroll
      for (int mf = 0; mf < 2; mf++)
        pa[mf] = *(const bf16x8*)&Pl[wave][(mf * 16 + (lane & 15)) * PSTR + kf * 32 + (lane >> 4) * 8];
#pragma unroll
      for (int nd = 0; nd < 4; nd++)
        vv[nd] = *(const bf16x8*)&Vt[(nd * 16 + (lane & 15)) * VSTR + kf * 32 + (lane >> 4) * 8];
#pragma unroll
      for (int mf = 0; mf < 2; mf++)
#pragma unroll
        for (int nd = 0; nd < 4; nd++) oacc[mf][nd] = mfma16(pa[mf], vv[nd], oacc[mf][nd]);
    }
  }

#pragma unroll
  for (int mf = 0; mf < 2; mf++) {
#pragma unroll
    for (int r = 0; r < 4; r++) {
      float rinv = 1.0f / lrow[mf][r];
      int irow = i0 + wave * 32 + mf * 16 + (lane >> 4) * 4 + r;
      bf16* orow = out + ((size_t)b * SEQ + irow) * DIM + h * HD;
#pragma unroll
      for (int nd = 0; nd < 4; nd++) orow[nd * 16 + (lane & 15)] = (bf16)(oacc[mf][nd][r] * rinv);
    }
  }
}

// ---------- workspace layout ----------
constexpr size_t OFF_WQKV = 0;                                    // 1536x512 bf16
constexpr size_t OFF_WPROJ = OFF_WQKV + (size_t)1536 * 512 * 2;   // 512x512 bf16
constexpr size_t OFF_W1 = OFF_WPROJ + (size_t)512 * 512 * 2;      // 2048x512 bf16
constexpr size_t OFF_W2 = OFF_W1 + (size_t)2048 * 512 * 2;        // 512x2048 bf16
constexpr size_t OFF_XW = OFF_W2 + (size_t)512 * 2048 * 2;        // 8192x512 bf16 (x / y1)
constexpr size_t OFF_SHARED = OFF_XW + (size_t)NROWS * DIM * 2;   // qkv (24MB) / ffn1 (32MB)
constexpr size_t OFF_ATTNOUT = OFF_SHARED + (size_t)NROWS * 2048 * 2;  // 8192x512 bf16
constexpr size_t WS_NEED = OFF_ATTNOUT + (size_t)NROWS * DIM * 2;      // ~56.6 MB

extern "C" void kernel_launch(void* const* d_in, const int* in_sizes, int n_in,
                              void* d_out, int out_size, void* d_ws, size_t ws_size,
                              hipStream_t stream) {
  const float* H = (const float*)d_in[0];
  const float* A = (const float*)d_in[1];
  const float* ln1_g = (const float*)d_in[2];
  const float* ln1_b = (const float*)d_in[3];
  const float* qkv_w = (const float*)d_in[4];
  const float* qkv_b = (const float*)d_in[5];
  const float* proj_w = (const float*)d_in[6];
  const float* proj_b = (const float*)d_in[7];
  const float* ln2_g = (const float*)d_in[8];
  const float* ln2_b = (const float*)d_in[9];
  const float* w1 = (const float*)d_in[10];
  const float* b1 = (const float*)d_in[11];
  const float* w2 = (const float*)d_in[12];
  const float* b2 = (const float*)d_in[13];
  const float* edge_w = (const float*)d_in[14];
  const float* edge_scale = (const float*)d_in[15];
  float* out = (float*)d_out;
  char* ws = (char*)d_ws;

  bf16* wqkv = (bf16*)(ws + OFF_WQKV);
  bf16* wproj = (bf16*)(ws + OFF_WPROJ);
  bf16* w1t = (bf16*)(ws + OFF_W1);
  bf16* w2t = (bf16*)(ws + OFF_W2);
  bf16* xw = (bf16*)(ws + OFF_XW);
  bf16* qkvb = (bf16*)(ws + OFF_SHARED);
  bf16* ffn1 = (bf16*)(ws + OFF_SHARED);
  bf16* attnout = (bf16*)(ws + OFF_ATTNOUT);

  // weights -> bf16 transposed (N,K)
  convert_t<512, 1536><<<512 * 1536 / 256, 256, 0, stream>>>(qkv_w, wqkv);
  convert_t<512, 512><<<512 * 512 / 256, 256, 0, stream>>>(proj_w, wproj);
  convert_t<512, 2048><<<512 * 2048 / 256, 256, 0, stream>>>(w1, w1t);
  convert_t<2048, 512><<<2048 * 512 / 256, 256, 0, stream>>>(w2, w2t);

  // x = LN1(H)
  ln_kernel<<<NROWS / 4, 256, 0, stream>>>(H, ln1_g, ln1_b, xw);
  // qkv = x @ qkv_w + qkv_b
  gemm_bt<EPI_BF16><<<dim3(1536 / GBN, NROWS / GBM), 256, 0, stream>>>(
      xw, wqkv, qkv_b, nullptr, qkvb, NROWS, 1536, 512);
  // attention
  attn_kernel<<<dim3(SEQ / 128, NHEAD, BATCH), 256, 0, stream>>>(qkvb, A, edge_w, edge_scale,
                                                                 attnout);
  // H2 = H + attnout @ proj_w + proj_b   (f32, into d_out)
  gemm_bt<EPI_RESID><<<dim3(512 / GBN, NROWS / GBM), 256, 0, stream>>>(
      attnout, wproj, proj_b, H, out, NROWS, 512, 512);
  // y1 = LN2(H2)
  ln_kernel<<<NROWS / 4, 256, 0, stream>>>(out, ln2_g, ln2_b, xw);
  // ffn1 = gelu(y1 @ w1 + b1)
  gemm_bt<EPI_GELU><<<dim3(2048 / GBN, NROWS / GBM), 256, 0, stream>>>(
      xw, w1t, b1, nullptr, ffn1, NROWS, 2048, 512);
  // out = H2 + ffn1 @ w2 + b2
  gemm_bt<EPI_RESID><<<dim3(512 / GBN, NROWS / GBM), 256, 0, stream>>>(
      ffn1, w2t, b2, out, out, NROWS, 512, 2048);
}

// Round 5
// 271.863 us; speedup vs baseline: 1.4639x; 1.4639x over previous
//
#include <hip/hip_runtime.h>
#include <hip/hip_bf16.h>

#define DIM 512
#define NHEAD 8
#define HD 64
#define SEQ 2048
#define BATCH 4
#define NROWS (BATCH * SEQ)  // 8192

typedef __bf16 bf16;
typedef __bf16 bf16x8 __attribute__((ext_vector_type(8)));
typedef __bf16 bf16x4 __attribute__((ext_vector_type(4)));
typedef float f32x4 __attribute__((ext_vector_type(4)));
typedef unsigned short us8 __attribute__((ext_vector_type(8)));
typedef unsigned int u32x4 __attribute__((ext_vector_type(4)));

__device__ __forceinline__ f32x4 mfma16(bf16x8 a, bf16x8 b, f32x4 c) {
  return __builtin_amdgcn_mfma_f32_16x16x32_bf16(a, b, c, 0, 0, 0);
}

// ---------- A -> bf16 elementwise ----------
__global__ __launch_bounds__(256, 8) void convert_a(const float* __restrict__ in,
                                                    bf16* __restrict__ out) {
  int id = blockIdx.x * 256 + threadIdx.x;
  float4 v = ((const float4*)in)[id];
  bf16x4 o;
  o[0] = (bf16)v.x;
  o[1] = (bf16)v.y;
  o[2] = (bf16)v.z;
  o[3] = (bf16)v.w;
  ((bf16x4*)out)[id] = o;
}

// ---------- LDS-tiled transpose + f32->bf16: in (R,C) -> out (C,R) ----------
template <int R, int C>
__global__ __launch_bounds__(256, 8) void convert_t(const float* __restrict__ in,
                                                    bf16* __restrict__ out) {
  __shared__ float tile[32][33];
  const int bx = blockIdx.x % (C / 32);
  const int by = blockIdx.x / (C / 32);
  const int tx = threadIdx.x & 31, ty = threadIdx.x >> 5;  // 32 x 8
#pragma unroll
  for (int i = 0; i < 32; i += 8)
    tile[ty + i][tx] = in[(size_t)(by * 32 + ty + i) * C + bx * 32 + tx];
  __syncthreads();
#pragma unroll
  for (int i = 0; i < 32; i += 8)
    out[(size_t)(bx * 32 + ty + i) * R + by * 32 + tx] = (bf16)tile[tx][ty + i];
}

// ---------- layernorm over 512 cols, one wave per row, bf16 out ----------
__global__ __launch_bounds__(256, 8) void ln_kernel(const float* __restrict__ in,
                                                    const float* __restrict__ g,
                                                    const float* __restrict__ b,
                                                    bf16* __restrict__ out) {
  int row = blockIdx.x * 4 + (threadIdx.x >> 6);
  int lane = threadIdx.x & 63;
  const float4* p = (const float4*)(in + (size_t)row * DIM);
  float4 v0 = p[lane];
  float4 v1 = p[lane + 64];
  float s = v0.x + v0.y + v0.z + v0.w + v1.x + v1.y + v1.z + v1.w;
#pragma unroll
  for (int m = 1; m < 64; m <<= 1) s += __shfl_xor(s, m);
  float mean = s * (1.0f / DIM);
  float d0 = v0.x - mean, d1 = v0.y - mean, d2 = v0.z - mean, d3 = v0.w - mean;
  float d4 = v1.x - mean, d5 = v1.y - mean, d6 = v1.z - mean, d7 = v1.w - mean;
  float q = d0 * d0 + d1 * d1 + d2 * d2 + d3 * d3 + d4 * d4 + d5 * d5 + d6 * d6 + d7 * d7;
#pragma unroll
  for (int m = 1; m < 64; m <<= 1) q += __shfl_xor(q, m);
  float rstd = rsqrtf(q * (1.0f / DIM) + 1e-5f);
  const float4* gp = (const float4*)g;
  const float4* bp = (const float4*)b;
  float4 g0 = gp[lane], g1 = gp[lane + 64];
  float4 b0 = bp[lane], b1 = bp[lane + 64];
  bf16x4 oa, ob;
  oa[0] = (bf16)(d0 * rstd * g0.x + b0.x);
  oa[1] = (bf16)(d1 * rstd * g0.y + b0.y);
  oa[2] = (bf16)(d2 * rstd * g0.z + b0.z);
  oa[3] = (bf16)(d3 * rstd * g0.w + b0.w);
  ob[0] = (bf16)(d4 * rstd * g1.x + b1.x);
  ob[1] = (bf16)(d5 * rstd * g1.y + b1.y);
  ob[2] = (bf16)(d6 * rstd * g1.z + b1.z);
  ob[3] = (bf16)(d7 * rstd * g1.w + b1.w);
  *(bf16x4*)(out + (size_t)row * DIM + lane * 4) = oa;
  *(bf16x4*)(out + (size_t)row * DIM + 256 + lane * 4) = ob;
}

// ---------- GEMM: C = A(MxK,bf16,rm) * Bt(NxK,bf16,rm)^T + bias, epilogues ----------
#define GBM 128
#define GBN 128
#define GBK 64
#define LSTR 88

enum { EPI_BF16 = 0, EPI_GELU = 1, EPI_RESID = 2 };

template <int EPI>
__global__ __launch_bounds__(256, 2) void gemm_bt(const bf16* __restrict__ A,
                                                  const bf16* __restrict__ Bt,
                                                  const float* __restrict__ bias,
                                                  const float* resid, void* outv,
                                                  int M, int N, int K) {
  __shared__ bf16 Al[GBM * LSTR];
  __shared__ bf16 Bl[GBN * LSTR];
  const int t = threadIdx.x;
  const int lane = t & 63;
  const int wave = t >> 6;
  const int wm = wave >> 1, wn = wave & 1;
  const int m0 = blockIdx.y * GBM, n0 = blockIdx.x * GBN;

  f32x4 acc[4][4] = {};

  const int srow = t >> 1;
  const int scol = (t & 1) * 32;
  const bf16* ga = A + (size_t)(m0 + srow) * K + scol;
  const bf16* gb = Bt + (size_t)(n0 + srow) * K + scol;
  bf16* la = &Al[srow * LSTR + scol];
  bf16* lb = &Bl[srow * LSTR + scol];

  for (int k0 = 0; k0 < K; k0 += GBK) {
    u32x4 ra0 = *(const u32x4*)(ga);
    u32x4 ra1 = *(const u32x4*)(ga + 8);
    u32x4 ra2 = *(const u32x4*)(ga + 16);
    u32x4 ra3 = *(const u32x4*)(ga + 24);
    u32x4 rb0 = *(const u32x4*)(gb);
    u32x4 rb1 = *(const u32x4*)(gb + 8);
    u32x4 rb2 = *(const u32x4*)(gb + 16);
    u32x4 rb3 = *(const u32x4*)(gb + 24);
    ga += GBK;
    gb += GBK;
    __syncthreads();
    ((u32x4*)la)[0] = ra0;
    ((u32x4*)la)[1] = ra1;
    ((u32x4*)la)[2] = ra2;
    ((u32x4*)la)[3] = ra3;
    ((u32x4*)lb)[0] = rb0;
    ((u32x4*)lb)[1] = rb1;
    ((u32x4*)lb)[2] = rb2;
    ((u32x4*)lb)[3] = rb3;
    __syncthreads();
#pragma unroll
    for (int kk = 0; kk < GBK; kk += 32) {
      bf16x8 af[4], bfr[4];
#pragma unroll
      for (int i = 0; i < 4; i++)
        af[i] = *(const bf16x8*)&Al[(wm * 64 + i * 16 + (lane & 15)) * LSTR + kk + (lane >> 4) * 8];
#pragma unroll
      for (int j = 0; j < 4; j++)
        bfr[j] = *(const bf16x8*)&Bl[(wn * 64 + j * 16 + (lane & 15)) * LSTR + kk + (lane >> 4) * 8];
#pragma unroll
      for (int i = 0; i < 4; i++)
#pragma unroll
        for (int j = 0; j < 4; j++) acc[i][j] = mfma16(af[i], bfr[j], acc[i][j]);
    }
  }
  const int rbase = (lane >> 4) * 4;
  const int cl = lane & 15;
#pragma unroll
  for (int i = 0; i < 4; i++) {
#pragma unroll
    for (int j = 0; j < 4; j++) {
      int col = n0 + wn * 64 + j * 16 + cl;
      float bv = bias[col];
#pragma unroll
      for (int r = 0; r < 4; r++) {
        int row = m0 + wm * 64 + i * 16 + rbase + r;
        float v = acc[i][j][r] + bv;
        size_t idx = (size_t)row * N + col;
        if constexpr (EPI == EPI_BF16) {
          ((bf16*)outv)[idx] = (bf16)v;
        } else if constexpr (EPI == EPI_GELU) {
          ((bf16*)outv)[idx] = (bf16)(0.5f * v * (1.0f + erff(v * 0.70710678118f)));
        } else {
          ((float*)outv)[idx] = resid[idx] + v;
        }
      }
    }
  }
}

// ---------- fused attention, swapped-QK^T flash ----------
#define KSTR 88
#define VSTR 136
#define PSTR 136

__global__ __launch_bounds__(256, 2) void attn_kernel(const bf16* __restrict__ qkv,
                                                      const bf16* __restrict__ Ab,
                                                      const float* __restrict__ edge_w,
                                                      const float* __restrict__ edge_scale,
                                                      bf16* __restrict__ out) {
  __shared__ bf16 Kl[128 * KSTR];
  __shared__ bf16 Vt[64 * VSTR];
  __shared__ bf16 Pl[4][32 * PSTR];
  const int i0 = blockIdx.x * 128;
  const int h = blockIdx.y;
  const int b = blockIdx.z;
  const int t = threadIdx.x, lane = t & 63, wave = t >> 6;
  const float LOG2E = 1.44269504089f;
  const float qs = 0.125f * LOG2E;                    // applied to (S + 8*es*A)
  const float esq = edge_scale[0] * edge_w[h] * 8.0f; // bias pre-divided by 0.125

  const int rs = 3 * DIM;  // 1536
  const bf16* qbase = qkv + (size_t)b * SEQ * rs + h * HD;
  const bf16* kbase = qbase + DIM;
  const bf16* vbase = qbase + 2 * DIM;

  // Q fragments (used as MFMA B-operand -> supplies Q^T)
  bf16x8 qf[2][2];
#pragma unroll
  for (int mf = 0; mf < 2; mf++)
#pragma unroll
    for (int kf = 0; kf < 2; kf++)
      qf[mf][kf] = *(const bf16x8*)(qbase + (size_t)(i0 + wave * 32 + mf * 16 + (lane & 15)) * rs +
                                    kf * 32 + (lane >> 4) * 8);

  // bias base: row i = i0 + wave*32 + mf*16 + (lane&15); col j = jt + nf*16 + (lane>>4)*4 + r
  const bf16* abase = Ab + ((size_t)b * SEQ + i0 + wave * 32 + (lane & 15)) * SEQ + (lane >> 4) * 4;

  float mreg[2] = {-1e30f, -1e30f};
  float lreg[2] = {0.0f, 0.0f};
  f32x4 oacc[2][4] = {};

  const int srow = t >> 1, scol = (t & 1) * 32;
  const int jp = t & 63;
  const int doct0 = t >> 6;

  for (int jt = 0; jt < SEQ; jt += 128) {
    // --- prefetch bias tile into registers (vectorized, coalesced) ---
    bf16x4 apre[2][8];
#pragma unroll
    for (int mf = 0; mf < 2; mf++)
#pragma unroll
      for (int nf = 0; nf < 8; nf++)
        apre[mf][nf] = *(const bf16x4*)(abase + (size_t)mf * 16 * SEQ + jt + nf * 16);

    // --- stage K, V ---
    const bf16* krow = kbase + (size_t)(jt + srow) * rs + scol;
    u32x4 rk0 = *(const u32x4*)(krow);
    u32x4 rk1 = *(const u32x4*)(krow + 8);
    u32x4 rk2 = *(const u32x4*)(krow + 16);
    u32x4 rk3 = *(const u32x4*)(krow + 24);
    const bf16* vr0 = vbase + (size_t)(jt + 2 * jp) * rs;
    const bf16* vr1 = vr0 + rs;
    us8 va0 = *(const us8*)(vr0 + doct0 * 8);
    us8 va1 = *(const us8*)(vr1 + doct0 * 8);
    us8 vb0 = *(const us8*)(vr0 + (doct0 + 4) * 8);
    us8 vb1 = *(const us8*)(vr1 + (doct0 + 4) * 8);
    __syncthreads();
    {
      u32x4* lk = (u32x4*)&Kl[srow * KSTR + scol];
      lk[0] = rk0;
      lk[1] = rk1;
      lk[2] = rk2;
      lk[3] = rk3;
#pragma unroll
      for (int jj = 0; jj < 8; jj++) {
        unsigned w0 = (unsigned)va0[jj] | ((unsigned)va1[jj] << 16);
        *(unsigned*)&Vt[(doct0 * 8 + jj) * VSTR + 2 * jp] = w0;
        unsigned w1 = (unsigned)vb0[jj] | ((unsigned)vb1[jj] << 16);
        *(unsigned*)&Vt[((doct0 + 4) * 8 + jj) * VSTR + 2 * jp] = w1;
      }
    }
    __syncthreads();

    // --- S^T = K Q^T, accumulator initialized with bias/scale ---
    f32x4 st[8][2];
#pragma unroll
    for (int nf = 0; nf < 8; nf++)
#pragma unroll
      for (int mf = 0; mf < 2; mf++)
#pragma unroll
        for (int r = 0; r < 4; r++) st[nf][mf][r] = esq * (float)apre[mf][nf][r];

#pragma unroll
    for (int kf = 0; kf < 2; kf++) {
      bf16x8 kfr[8];
#pragma unroll
      for (int nf = 0; nf < 8; nf++)
        kfr[nf] = *(const bf16x8*)&Kl[(nf * 16 + (lane & 15)) * KSTR + kf * 32 + (lane >> 4) * 8];
#pragma unroll
      for (int nf = 0; nf < 8; nf++)
#pragma unroll
        for (int mf = 0; mf < 2; mf++) st[nf][mf] = mfma16(kfr[nf], qf[mf][kf], st[nf][mf]);
    }

    // --- online softmax over j (rows of S^T): in-register + 2 shuffles ---
#pragma unroll
    for (int mf = 0; mf < 2; mf++) {
      float rmax = -1e30f;
#pragma unroll
      for (int nf = 0; nf < 8; nf++)
#pragma unroll
        for (int r = 0; r < 4; r++) {
          float v = st[nf][mf][r] * qs;
          st[nf][mf][r] = v;
          rmax = fmaxf(rmax, v);
        }
      rmax = fmaxf(rmax, __shfl_xor(rmax, 16));
      rmax = fmaxf(rmax, __shfl_xor(rmax, 32));
      float mnew = fmaxf(mreg[mf], rmax);
      float corr = exp2f(mreg[mf] - mnew);
      mreg[mf] = mnew;
      float psum = 0.0f;
      const int ibase = (mf * 16 + (lane & 15)) * PSTR + (lane >> 4) * 4;
#pragma unroll
      for (int nf = 0; nf < 8; nf++) {
        bf16x4 pk;
#pragma unroll
        for (int r = 0; r < 4; r++) {
          float p = exp2f(st[nf][mf][r] - mnew);
          psum += p;
          pk[r] = (bf16)p;
        }
        *(bf16x4*)&Pl[wave][ibase + nf * 16] = pk;
      }
      psum += __shfl_xor(psum, 16);
      psum += __shfl_xor(psum, 32);
      lreg[mf] = lreg[mf] * corr + psum;
      // broadcast corr to the O-fragment row layout and rescale
#pragma unroll
      for (int r = 0; r < 4; r++) {
        float c = __shfl(corr, (lane >> 4) * 4 + r);
#pragma unroll
        for (int nd = 0; nd < 4; nd++) oacc[mf][nd][r] *= c;
      }
    }

    // --- O += P V ---
#pragma unroll
    for (int kf = 0; kf < 4; kf++) {
      bf16x8 pa[2], vv[4];
#pragma unroll
      for (int mf = 0; mf < 2; mf++)
        pa[mf] = *(const bf16x8*)&Pl[wave][(mf * 16 + (lane & 15)) * PSTR + kf * 32 + (lane >> 4) * 8];
#pragma unroll
      for (int nd = 0; nd < 4; nd++)
        vv[nd] = *(const bf16x8*)&Vt[(nd * 16 + (lane & 15)) * VSTR + kf * 32 + (lane >> 4) * 8];
#pragma unroll
      for (int mf = 0; mf < 2; mf++)
#pragma unroll
        for (int nd = 0; nd < 4; nd++) oacc[mf][nd] = mfma16(pa[mf], vv[nd], oacc[mf][nd]);
    }
  }

#pragma unroll
  for (int mf = 0; mf < 2; mf++) {
#pragma unroll
    for (int r = 0; r < 4; r++) {
      float li = __shfl(lreg[mf], (lane >> 4) * 4 + r);
      float rinv = 1.0f / li;
      int irow = i0 + wave * 32 + mf * 16 + (lane >> 4) * 4 + r;
      bf16* orow = out + ((size_t)b * SEQ + irow) * DIM + h * HD;
#pragma unroll
      for (int nd = 0; nd < 4; nd++) orow[nd * 16 + (lane & 15)] = (bf16)(oacc[mf][nd][r] * rinv);
    }
  }
}

// ---------- workspace layout ----------
constexpr size_t OFF_WQKV = 0;                                    // 1536x512 bf16
constexpr size_t OFF_WPROJ = OFF_WQKV + (size_t)1536 * 512 * 2;   // 512x512 bf16
constexpr size_t OFF_W1 = OFF_WPROJ + (size_t)512 * 512 * 2;      // 2048x512 bf16
constexpr size_t OFF_W2 = OFF_W1 + (size_t)2048 * 512 * 2;        // 512x2048 bf16
constexpr size_t OFF_XW = OFF_W2 + (size_t)512 * 2048 * 2;        // 8192x512 bf16 (x / y1)
constexpr size_t OFF_SHARED = OFF_XW + (size_t)NROWS * DIM * 2;   // qkv (24MB) / ffn1 (32MB)
constexpr size_t OFF_ATTNOUT = OFF_SHARED + (size_t)NROWS * 2048 * 2;  // 8192x512 bf16
constexpr size_t OFF_AB16 = OFF_ATTNOUT + (size_t)NROWS * DIM * 2;     // 4x2048x2048 bf16
constexpr size_t WS_NEED = OFF_AB16 + (size_t)BATCH * SEQ * SEQ * 2;   // ~90 MB

extern "C" void kernel_launch(void* const* d_in, const int* in_sizes, int n_in,
                              void* d_out, int out_size, void* d_ws, size_t ws_size,
                              hipStream_t stream) {
  const float* H = (const float*)d_in[0];
  const float* A = (const float*)d_in[1];
  const float* ln1_g = (const float*)d_in[2];
  const float* ln1_b = (const float*)d_in[3];
  const float* qkv_w = (const float*)d_in[4];
  const float* qkv_b = (const float*)d_in[5];
  const float* proj_w = (const float*)d_in[6];
  const float* proj_b = (const float*)d_in[7];
  const float* ln2_g = (const float*)d_in[8];
  const float* ln2_b = (const float*)d_in[9];
  const float* w1 = (const float*)d_in[10];
  const float* b1 = (const float*)d_in[11];
  const float* w2 = (const float*)d_in[12];
  const float* b2 = (const float*)d_in[13];
  const float* edge_w = (const float*)d_in[14];
  const float* edge_scale = (const float*)d_in[15];
  float* out = (float*)d_out;
  char* ws = (char*)d_ws;

  bf16* wqkv = (bf16*)(ws + OFF_WQKV);
  bf16* wproj = (bf16*)(ws + OFF_WPROJ);
  bf16* w1t = (bf16*)(ws + OFF_W1);
  bf16* w2t = (bf16*)(ws + OFF_W2);
  bf16* xw = (bf16*)(ws + OFF_XW);
  bf16* qkvb = (bf16*)(ws + OFF_SHARED);
  bf16* ffn1 = (bf16*)(ws + OFF_SHARED);
  bf16* attnout = (bf16*)(ws + OFF_ATTNOUT);
  bf16* ab16 = (bf16*)(ws + OFF_AB16);

  // A -> bf16 (16.8M elems, 4 per thread)
  convert_a<<<BATCH * SEQ * SEQ / 4 / 256, 256, 0, stream>>>(A, ab16);
  // weights -> bf16 transposed (N,K), LDS-tiled
  convert_t<512, 1536><<<(512 / 32) * (1536 / 32), 256, 0, stream>>>(qkv_w, wqkv);
  convert_t<512, 512><<<(512 / 32) * (512 / 32), 256, 0, stream>>>(proj_w, wproj);
  convert_t<512, 2048><<<(512 / 32) * (2048 / 32), 256, 0, stream>>>(w1, w1t);
  convert_t<2048, 512><<<(2048 / 32) * (512 / 32), 256, 0, stream>>>(w2, w2t);

  // x = LN1(H)
  ln_kernel<<<NROWS / 4, 256, 0, stream>>>(H, ln1_g, ln1_b, xw);
  // qkv = x @ qkv_w + qkv_b
  gemm_bt<EPI_BF16><<<dim3(1536 / GBN, NROWS / GBM), 256, 0, stream>>>(
      xw, wqkv, qkv_b, nullptr, qkvb, NROWS, 1536, 512);
  // attention
  attn_kernel<<<dim3(SEQ / 128, NHEAD, BATCH), 256, 0, stream>>>(qkvb, ab16, edge_w, edge_scale,
                                                                 attnout);
  // H2 = H + attnout @ proj_w + proj_b   (f32, into d_out)
  gemm_bt<EPI_RESID><<<dim3(512 / GBN, NROWS / GBM), 256, 0, stream>>>(
      attnout, wproj, proj_b, H, out, NROWS, 512, 512);
  // y1 = LN2(H2)
  ln_kernel<<<NROWS / 4, 256, 0, stream>>>(out, ln2_g, ln2_b, xw);
  // ffn1 = gelu(y1 @ w1 + b1)
  gemm_bt<EPI_GELU><<<dim3(2048 / GBN, NROWS / GBM), 256, 0, stream>>>(
      xw, w1t, b1, nullptr, ffn1, NROWS, 2048, 512);
  // out = H2 + ffn1 @ w2 + b2
  gemm_bt<EPI_RESID><<<dim3(512 / GBN, NROWS / GBM), 256, 0, stream>>>(
      ffn1, w2t, b2, out, out, NROWS, 512, 2048);
}